// Round 1
// baseline (1106.098 us; speedup 1.0000x reference)
//
#include <hip/hip_runtime.h>
#include <cmath>

#define BQ 300
#define DIM 256
#define NH 8
#define HD 32
#define NB 32
#define MROWS 9600
#define SENC 8400

// ---------------- GEMM ----------------
// C[M,N] = act( (A @ W + bias) * alpha )
// mode 0: A = A1 (M x K)
// mode 1: A = A1 + A2 (both M x K)
// mode 2: A = concat(A1 [M x split], A2 [M x (K-split)]) along K
// act 0: none, 1: relu, 2: sigmoid
__global__ __launch_bounds__(256)
void gemm_f32(const float* __restrict__ A1, const float* __restrict__ A2,
              const float* __restrict__ W, const float* __restrict__ bias,
              float* __restrict__ C, int M, int N, int K, int split,
              float alpha, int mode, int act)
{
    __shared__ float As[16][65];   // [k][m], padded to kill ds_write bank conflict
    __shared__ float Bs[16][64];   // [k][n]
    const int tid = threadIdx.x;
    const int tx = tid & 15, ty = tid >> 4;
    const int row0 = blockIdx.y * 64, col0 = blockIdx.x * 64;
    float acc[4][4] = {};
    for (int k0 = 0; k0 < K; k0 += 16) {
        #pragma unroll
        for (int i = 0; i < 4; ++i) {
            int idx = tid + i * 256;
            int r = idx >> 4, c = idx & 15;
            int gr = row0 + r, gk = k0 + c;
            float v;
            if (mode == 0)      v = A1[(size_t)gr * K + gk];
            else if (mode == 1) v = A1[(size_t)gr * K + gk] + A2[(size_t)gr * K + gk];
            else                v = (gk < split) ? A1[(size_t)gr * split + gk]
                                                 : A2[(size_t)gr * (K - split) + (gk - split)];
            As[c][r] = v;
        }
        #pragma unroll
        for (int i = 0; i < 4; ++i) {
            int idx = tid + i * 256;
            int r = idx >> 6, c = idx & 63;
            int gc = col0 + c;
            Bs[r][c] = (gc < N) ? W[(size_t)(k0 + r) * N + gc] : 0.0f;
        }
        __syncthreads();
        #pragma unroll
        for (int kk = 0; kk < 16; ++kk) {
            float a[4], b[4];
            #pragma unroll
            for (int i = 0; i < 4; ++i) a[i] = As[kk][ty * 4 + i];
            #pragma unroll
            for (int j = 0; j < 4; ++j) b[j] = Bs[kk][tx * 4 + j];
            #pragma unroll
            for (int i = 0; i < 4; ++i)
                #pragma unroll
                for (int j = 0; j < 4; ++j)
                    acc[i][j] = fmaf(a[i], b[j], acc[i][j]);
        }
        __syncthreads();
    }
    #pragma unroll
    for (int i = 0; i < 4; ++i) {
        int r = row0 + ty * 4 + i;
        #pragma unroll
        for (int j = 0; j < 4; ++j) {
            int c = col0 + tx * 4 + j;
            if (c < N) {
                float v = acc[i][j];
                if (bias) v += bias[c];
                v *= alpha;
                if (act == 1) v = fmaxf(v, 0.0f);
                else if (act == 2) v = 1.0f / (1.0f + expf(-v));
                C[(size_t)r * N + c] = v;
            }
        }
    }
}

// ---------------- Self-attention (per b,h block) ----------------
__global__ __launch_bounds__(256)
void attn_kernel(const float* __restrict__ Qm, const float* __restrict__ Km,
                 const float* __restrict__ Vm, float* __restrict__ Om)
{
    const int bh = blockIdx.x;
    const int b = bh >> 3, h = bh & 7;
    __shared__ float ks[BQ][HD + 1];   // padded: conflict-free score dots
    __shared__ float vs[BQ][HD];
    __shared__ float qs[16][HD];
    __shared__ float ss[16][BQ];
    const int tid = threadIdx.x;

    for (int e = tid; e < BQ * HD; e += 256) {
        int key = e >> 5, d = e & 31;
        size_t gi = ((size_t)(b * BQ + key)) * DIM + h * HD + d;
        ks[key][d] = Km[gi];
        vs[key][d] = Vm[gi];
    }
    __syncthreads();

    for (int r0 = 0; r0 < BQ; r0 += 16) {
        const int nr = min(16, BQ - r0);
        for (int e = tid; e < nr * HD; e += 256) {
            int r = e >> 5, d = e & 31;
            qs[r][d] = Qm[((size_t)(b * BQ + r0 + r)) * DIM + h * HD + d];
        }
        __syncthreads();
        for (int e = tid; e < nr * BQ; e += 256) {
            int r = e / BQ, key = e % BQ;
            float a = 0.0f;
            #pragma unroll
            for (int d = 0; d < HD; ++d) a = fmaf(qs[r][d], ks[key][d], a);
            ss[r][key] = a;
        }
        __syncthreads();
        if (tid < nr * 16) {
            int r = tid >> 4, sub = tid & 15;
            float mx = -1e30f;
            for (int k2 = sub; k2 < BQ; k2 += 16) mx = fmaxf(mx, ss[r][k2]);
            for (int off = 8; off; off >>= 1) mx = fmaxf(mx, __shfl_xor(mx, off, 16));
            float sum = 0.0f;
            for (int k2 = sub; k2 < BQ; k2 += 16) {
                float e2 = expf(ss[r][k2] - mx);
                ss[r][k2] = e2;
                sum += e2;
            }
            for (int off = 8; off; off >>= 1) sum += __shfl_xor(sum, off, 16);
            float inv = 1.0f / sum;
            for (int k2 = sub; k2 < BQ; k2 += 16) ss[r][k2] *= inv;
        }
        __syncthreads();
        for (int e = tid; e < nr * HD; e += 256) {
            int r = e >> 5, d = e & 31;
            float a = 0.0f;
            for (int k2 = 0; k2 < BQ; ++k2) a = fmaf(ss[r][k2], vs[k2][d], a);
            Om[((size_t)(b * BQ + r0 + r)) * DIM + h * HD + d] = a;
        }
        __syncthreads();
    }
}

// ---------------- LayerNorm (wave per row) ----------------
// mode 0: t = x + y
// mode 1: t = G[c]*x + G[c+256]*y  (G row stride 512, sigmoid already applied)
__global__ __launch_bounds__(256)
void ln_kernel(const float* __restrict__ X, const float* __restrict__ Y,
               const float* __restrict__ G,
               const float* __restrict__ w, const float* __restrict__ b,
               float* __restrict__ out, int mode)
{
    const int row = blockIdx.x * 4 + (threadIdx.x >> 6);
    const int lane = threadIdx.x & 63;
    const float* xr = X + (size_t)row * DIM;
    const float* yr = Y + (size_t)row * DIM;
    const float* gr = G ? G + (size_t)row * 512 : nullptr;
    float v[4];
    #pragma unroll
    for (int i = 0; i < 4; ++i) {
        int c = lane + 64 * i;
        if (mode == 0) v[i] = xr[c] + yr[c];
        else           v[i] = gr[c] * xr[c] + gr[c + 256] * yr[c];
    }
    float s = v[0] + v[1] + v[2] + v[3];
    float s2 = v[0]*v[0] + v[1]*v[1] + v[2]*v[2] + v[3]*v[3];
    #pragma unroll
    for (int off = 32; off; off >>= 1) {
        s  += __shfl_xor(s, off);
        s2 += __shfl_xor(s2, off);
    }
    const float mean = s * (1.0f / DIM);
    const float var = s2 * (1.0f / DIM) - mean * mean;
    const float inv = rsqrtf(var + 1e-5f);
    #pragma unroll
    for (int i = 0; i < 4; ++i) {
        int c = lane + 64 * i;
        out[(size_t)row * DIM + c] = (v[i] - mean) * inv * w[c] + b[c];
    }
}

// ---------------- softmax over 12 points ----------------
__global__ __launch_bounds__(256)
void softmax12(float* __restrict__ aw)
{
    const int i = blockIdx.x * 256 + threadIdx.x;   // 0 .. 76799
    float* p = aw + (size_t)i * 12;
    float mx = -1e30f;
    #pragma unroll
    for (int j = 0; j < 12; ++j) mx = fmaxf(mx, p[j]);
    float s = 0.0f;
    float e[12];
    #pragma unroll
    for (int j = 0; j < 12; ++j) { e[j] = expf(p[j] - mx); s += e[j]; }
    const float inv = 1.0f / s;
    #pragma unroll
    for (int j = 0; j < 12; ++j) p[j] = e[j] * inv;
}

// ---------------- deformable sampling ----------------
// block = (b,q); thread = (h,d). ca[b,q,h*32+d] = sum_p aw * bilinear(enc)
__global__ __launch_bounds__(256)
void sample_kernel(const float* __restrict__ enc, const float* __restrict__ offs,
                   const float* __restrict__ aw, const float* __restrict__ ref,
                   float* __restrict__ ca)
{
    const int bq = blockIdx.x;
    const int b = bq / BQ;
    const int t = threadIdx.x;
    const int h = t >> 5, d = t & 31;
    const float* rp = ref + (size_t)bq * 4;
    const float rx = rp[0], ry = rp[1], rw = rp[2], rh = rp[3];
    const float* op = offs + ((size_t)bq * 8 + h) * 24;
    const float* ap = aw + ((size_t)bq * 8 + h) * 12;
    float acc = 0.0f;
    int p = 0;
    #pragma unroll
    for (int l = 0; l < 3; ++l) {
        const int Wl = (l == 0) ? 80 : (l == 1 ? 40 : 20);
        const int Hl = Wl;
        const int soff = (l == 0) ? 0 : (l == 1 ? 6400 : 8000);
        const float* base = enc + ((size_t)(b * SENC + soff)) * DIM + h * HD + d;
        #pragma unroll
        for (int pp = 0; pp < 4; ++pp, ++p) {
            const float ox = op[p * 2 + 0], oy = op[p * 2 + 1];
            const float lx = rx + ox * 0.25f * rw * 0.5f;
            const float ly = ry + oy * 0.25f * rh * 0.5f;
            const float gx = lx * (float)Wl - 0.5f;
            const float gy = ly * (float)Hl - 0.5f;
            const float x0f = floorf(gx), y0f = floorf(gy);
            const int x0 = (int)x0f, y0 = (int)y0f;
            const float wx1 = gx - x0f, wy1 = gy - y0f;
            const float wx0 = 1.0f - wx1, wy0 = 1.0f - wy1;
            float sv = 0.0f;
            const bool vx0 = (x0 >= 0) & (x0 < Wl);
            const bool vx1 = (x0 + 1 >= 0) & (x0 + 1 < Wl);
            const bool vy0 = (y0 >= 0) & (y0 < Hl);
            const bool vy1 = (y0 + 1 >= 0) & (y0 + 1 < Hl);
            if (vx0 & vy0) sv = fmaf(wx0 * wy0, base[((size_t)(y0 * Wl + x0)) * DIM], sv);
            if (vx1 & vy0) sv = fmaf(wx1 * wy0, base[((size_t)(y0 * Wl + x0 + 1)) * DIM], sv);
            if (vx0 & vy1) sv = fmaf(wx0 * wy1, base[((size_t)((y0 + 1) * Wl + x0)) * DIM], sv);
            if (vx1 & vy1) sv = fmaf(wx1 * wy1, base[((size_t)((y0 + 1) * Wl + x0 + 1)) * DIM], sv);
            acc = fmaf(ap[p], sv, acc);
        }
    }
    ca[(size_t)bq * DIM + h * HD + d] = acc;
}

extern "C" void kernel_launch(void* const* d_in, const int* in_sizes, int n_in,
                              void* d_out, int out_size, void* d_ws, size_t ws_size,
                              hipStream_t stream)
{
    (void)in_sizes; (void)n_in; (void)out_size; (void)ws_size;
    const float* hidden   = (const float*)d_in[0];
    const float* pos      = (const float*)d_in[1];
    const float* ref      = (const float*)d_in[2];
    const float* enc      = (const float*)d_in[3];
    const float* q_w      = (const float*)d_in[4];
    const float* q_b      = (const float*)d_in[5];
    const float* k_w      = (const float*)d_in[6];
    const float* k_b      = (const float*)d_in[7];
    const float* v_w      = (const float*)d_in[8];
    const float* v_b      = (const float*)d_in[9];
    const float* o_w      = (const float*)d_in[10];
    const float* o_b      = (const float*)d_in[11];
    const float* sa_ln_w  = (const float*)d_in[12];
    const float* sa_ln_b  = (const float*)d_in[13];
    const float* off_w    = (const float*)d_in[14];
    const float* off_b    = (const float*)d_in[15];
    const float* aw_w     = (const float*)d_in[16];
    const float* aw_b     = (const float*)d_in[17];
    const float* gate_w   = (const float*)d_in[18];
    const float* gate_b   = (const float*)d_in[19];
    const float* gate_ln_w= (const float*)d_in[20];
    const float* gate_ln_b= (const float*)d_in[21];
    const float* fc1_w    = (const float*)d_in[22];
    const float* fc1_b    = (const float*)d_in[23];
    const float* fc2_w    = (const float*)d_in[24];
    const float* fc2_b    = (const float*)d_in[25];
    const float* fin_ln_w = (const float*)d_in[26];
    const float* fin_ln_b = (const float*)d_in[27];
    float* out = (float*)d_out;

    float* ws = (float*)d_ws;
    const size_t SEG = (size_t)MROWS * DIM;   // 2,457,600 floats
    float* HQb = ws;            // attn_out, then h2
    float* Qb  = ws + SEG;      // q, then sa_out, then offs, then gates/mid
    float* Kb  = ws + 2 * SEG;  // k, then aw
    float* Vb  = ws + 3 * SEG;  // v, then ca
    float* H1  = ws + 4 * SEG;  // post-SA hidden
    float* gates = Qb;          // 9600 x 512 spans Qb..Kb
    float* mid   = Qb;          // 9600 x 1024 spans Qb..H1 end

    const dim3 blk(256);
    const float scal = 0.17677669529663687f;  // 32^-0.5

    // q/k from hidden+pos, v from hidden
    gemm_f32<<<dim3(4, 150), blk, 0, stream>>>(hidden, pos, q_w, q_b, Qb, MROWS, 256, 256, 0, scal, 1, 0);
    gemm_f32<<<dim3(4, 150), blk, 0, stream>>>(hidden, pos, k_w, k_b, Kb, MROWS, 256, 256, 0, 1.0f, 1, 0);
    gemm_f32<<<dim3(4, 150), blk, 0, stream>>>(hidden, nullptr, v_w, v_b, Vb, MROWS, 256, 256, 0, 1.0f, 0, 0);
    // self-attention
    attn_kernel<<<dim3(NB * NH), blk, 0, stream>>>(Qb, Kb, Vb, HQb);
    // output projection -> sa_out (Qb), then LN(hidden+sa) -> H1
    gemm_f32<<<dim3(4, 150), blk, 0, stream>>>(HQb, nullptr, o_w, o_b, Qb, MROWS, 256, 256, 0, 1.0f, 0, 0);
    ln_kernel<<<dim3(2400), blk, 0, stream>>>(Qb, hidden, nullptr, sa_ln_w, sa_ln_b, H1, 0);
    // offsets + attention weights
    gemm_f32<<<dim3(3, 150), blk, 0, stream>>>(H1, nullptr, off_w, off_b, Qb, MROWS, 192, 256, 0, 1.0f, 0, 0);
    gemm_f32<<<dim3(2, 150), blk, 0, stream>>>(H1, nullptr, aw_w, aw_b, Kb, MROWS, 96, 256, 0, 1.0f, 0, 0);
    softmax12<<<dim3(300), blk, 0, stream>>>(Kb);
    // deformable sampling -> ca (Vb)
    sample_kernel<<<dim3(MROWS), blk, 0, stream>>>(enc, Qb, Kb, ref, Vb);
    // gates = sigmoid(concat(H1, ca) @ gate_w + b) -> Qb..Kb ; h2 = LN(g1*H1 + g2*ca) -> HQb
    gemm_f32<<<dim3(8, 150), blk, 0, stream>>>(H1, Vb, gate_w, gate_b, gates, MROWS, 512, 512, 256, 1.0f, 2, 2);
    ln_kernel<<<dim3(2400), blk, 0, stream>>>(H1, Vb, gates, gate_ln_w, gate_ln_b, HQb, 1);
    // FFN: mid = relu(h2@fc1+b) ; ffn_out = mid@fc2+b -> out ; out = LN(out + h2)
    gemm_f32<<<dim3(16, 150), blk, 0, stream>>>(HQb, nullptr, fc1_w, fc1_b, mid, MROWS, 1024, 256, 0, 1.0f, 0, 1);
    gemm_f32<<<dim3(4, 150), blk, 0, stream>>>(mid, nullptr, fc2_w, fc2_b, out, MROWS, 256, 1024, 0, 1.0f, 0, 0);
    ln_kernel<<<dim3(2400), blk, 0, stream>>>(out, HQb, nullptr, fin_ln_w, fin_ln_b, out, 0);
}

// Round 2
// 449.144 us; speedup vs baseline: 2.4627x; 2.4627x over previous
//
#include <hip/hip_runtime.h>
#include <cmath>

#define BQ 300
#define DIM 256
#define NH 8
#define HD 32
#define NB 32
#define MROWS 9600
#define SENC 8400

typedef unsigned short ushort_t;
typedef __attribute__((ext_vector_type(8))) short short8;
typedef __attribute__((ext_vector_type(4))) float f32x4;
typedef __attribute__((ext_vector_type(4))) unsigned short us4;

__device__ __forceinline__ float bf2f(ushort_t u) {
    union { unsigned u32; float f; } x; x.u32 = ((unsigned)u) << 16; return x.f;
}
__device__ __forceinline__ ushort_t f2bf(float f) {
    union { float f; unsigned u; } x; x.f = f;
    unsigned u = x.u;
    u += 0x7fffu + ((u >> 16) & 1u);
    return (ushort_t)(u >> 16);
}

// ---------------- weight transpose + bf16 convert ----------------
// WT[n][k] = (n < N) ? bf16(W[k][n]) : 0   (WT is Npad x K row-major)
__global__ __launch_bounds__(256)
void wtrans(const float* __restrict__ W, ushort_t* __restrict__ WT,
            int K, int N, int Npad)
{
    __shared__ float t[32][33];
    const int tx = threadIdx.x & 31, ty = threadIdx.x >> 5;
    const int n0 = blockIdx.x * 32, k0 = blockIdx.y * 32;
    #pragma unroll
    for (int i = 0; i < 4; ++i) {
        int k = k0 + ty + i * 8, n = n0 + tx;
        t[ty + i * 8][tx] = (n < N) ? W[(size_t)k * N + n] : 0.0f;
    }
    __syncthreads();
    #pragma unroll
    for (int i = 0; i < 4; ++i) {
        int n = n0 + ty + i * 8;
        WT[(size_t)n * K + k0 + tx] = f2bf(t[tx][ty + i * 8]);
    }
}

// ---------------- f32 -> bf16 convert (optional add) ----------------
__global__ __launch_bounds__(256)
void cvt_add_bf16(const float* __restrict__ a, const float* __restrict__ b,
                  ushort_t* __restrict__ o, int n4)
{
    int i = blockIdx.x * 256 + threadIdx.x;
    if (i >= n4) return;
    float4 va = ((const float4*)a)[i];
    if (b) {
        float4 vb = ((const float4*)b)[i];
        va.x += vb.x; va.y += vb.y; va.z += vb.z; va.w += vb.w;
    }
    us4 u;
    u.x = f2bf(va.x); u.y = f2bf(va.y); u.z = f2bf(va.z); u.w = f2bf(va.w);
    *(us4*)&o[(size_t)i * 4] = u;
}

// ---------------- MFMA GEMM ----------------
// C = act((A @ B + bias) * alpha); A: M x K bf16 (lda), Bt: Npad x K bf16 (= B^T)
// grid: (Npad/BN, M/BM), 256 threads, 2x2 waves.
template<int BM, int BN, int ACT, bool OBF>
__global__ __launch_bounds__(256)
void gemm_mfma(const ushort_t* __restrict__ A, int lda,
               const ushort_t* __restrict__ Bt, int K,
               const float* __restrict__ bias, int N, float alpha,
               float* __restrict__ Cf, ushort_t* __restrict__ Cb, int ldc)
{
    constexpr int LDT = 40;   // 32 + 8 pad (keeps 16B align, spreads banks)
    __shared__ ushort_t As[BM * LDT];
    __shared__ ushort_t Bs[BN * LDT];
    const int tid = threadIdx.x;
    const int row0 = blockIdx.y * BM, col0 = blockIdx.x * BN;
    const int lane = tid & 63, wid = tid >> 6;
    const int wm = wid >> 1, wn = wid & 1;
    constexpr int FM = BM / 32, FN = BN / 32;
    const int r16 = lane & 15, kg = lane >> 4;

    f32x4 acc[FM][FN];
    #pragma unroll
    for (int m = 0; m < FM; ++m)
        #pragma unroll
        for (int n = 0; n < FN; ++n) {
            f32x4 z = {0.f, 0.f, 0.f, 0.f};
            acc[m][n] = z;
        }

    for (int k0 = 0; k0 < K; k0 += 32) {
        #pragma unroll
        for (int c = 0; c < BM * 4 / 256; ++c) {
            int idx = tid + c * 256;
            int r = idx >> 2, cc = idx & 3;
            *(short8*)&As[r * LDT + cc * 8] =
                *(const short8*)&A[(size_t)(row0 + r) * lda + k0 + cc * 8];
        }
        #pragma unroll
        for (int c = 0; c < BN * 4 / 256; ++c) {
            int idx = tid + c * 256;
            int r = idx >> 2, cc = idx & 3;
            *(short8*)&Bs[r * LDT + cc * 8] =
                *(const short8*)&Bt[(size_t)(col0 + r) * K + k0 + cc * 8];
        }
        __syncthreads();
        short8 a[FM], b[FN];
        #pragma unroll
        for (int m = 0; m < FM; ++m)
            a[m] = *(const short8*)&As[(wm * (BM / 2) + m * 16 + r16) * LDT + kg * 8];
        #pragma unroll
        for (int n = 0; n < FN; ++n)
            b[n] = *(const short8*)&Bs[(wn * (BN / 2) + n * 16 + r16) * LDT + kg * 8];
        #pragma unroll
        for (int m = 0; m < FM; ++m)
            #pragma unroll
            for (int n = 0; n < FN; ++n)
                acc[m][n] = __builtin_amdgcn_mfma_f32_16x16x32_bf16(a[m], b[n], acc[m][n], 0, 0, 0);
        __syncthreads();
    }

    #pragma unroll
    for (int m = 0; m < FM; ++m) {
        #pragma unroll
        for (int n = 0; n < FN; ++n) {
            int colb = col0 + wn * (BN / 2) + n * 16 + r16;
            float bs = (bias && colb < N) ? bias[colb] : 0.0f;
            #pragma unroll
            for (int r = 0; r < 4; ++r) {
                int row = row0 + wm * (BM / 2) + m * 16 + kg * 4 + r;
                float v = (acc[m][n][r] + bs) * alpha;
                if (ACT == 1) v = fmaxf(v, 0.0f);
                if (ACT == 2) v = 1.0f / (1.0f + __expf(-v));
                if (OBF) Cb[(size_t)row * ldc + colb] = f2bf(v);
                else     Cf[(size_t)row * ldc + colb] = v;
            }
        }
    }
}

// ---------------- flash-style self-attention ----------------
// grid: 32*8*10 blocks; block = (b, h, 32-row q chunk); 256 thr = 4 waves x 8 rows
__global__ __launch_bounds__(256)
void attn_flash(const ushort_t* __restrict__ Q, const ushort_t* __restrict__ K,
                const ushort_t* __restrict__ V, ushort_t* __restrict__ O)
{
    const int qc = blockIdx.x % 10;
    const int bh = blockIdx.x / 10;
    const int b = bh >> 3, h = bh & 7;
    const int q0 = qc * 32;
    const int nq = (BQ - q0 < 32) ? (BQ - q0) : 32;

    __shared__ float qs[32][34];
    __shared__ float ks[64][34];
    __shared__ float vs[64][34];
    __shared__ float ps[32][64];

    const int tid = threadIdx.x;
    const int lane = tid & 63, wid = tid >> 6;
    const int wq = wid * 8;
    const int dd = lane & 31, hi = lane >> 5;

    // stage Q chunk (scaled already in the q GEMM)
    {
        int c = tid;               // 32 rows * 8 chunks of 4 = 256
        int q = c >> 3, d4 = (c & 7) * 4;
        if (q < nq) {
            us4 u = *(const us4*)&Q[((size_t)(b * BQ + q0 + q)) * DIM + h * HD + d4];
            qs[q][d4 + 0] = bf2f(u.x); qs[q][d4 + 1] = bf2f(u.y);
            qs[q][d4 + 2] = bf2f(u.z); qs[q][d4 + 3] = bf2f(u.w);
        } else {
            qs[q][d4 + 0] = 0.f; qs[q][d4 + 1] = 0.f;
            qs[q][d4 + 2] = 0.f; qs[q][d4 + 3] = 0.f;
        }
    }
    float mrow[8], lrow[8], oacc[4];
    #pragma unroll
    for (int j = 0; j < 8; ++j) { mrow[j] = -1e30f; lrow[j] = 0.f; }
    #pragma unroll
    for (int i = 0; i < 4; ++i) oacc[i] = 0.f;
    __syncthreads();

    for (int kt = 0; kt < 5; ++kt) {
        #pragma unroll
        for (int c2 = 0; c2 < 2; ++c2) {
            int c = tid + c2 * 256;   // 64 rows * 8 chunks
            int kk = c >> 3, d4 = (c & 7) * 4;
            int ki = kt * 64 + kk;
            if (ki < BQ) {
                size_t gi = ((size_t)(b * BQ + ki)) * DIM + h * HD + d4;
                us4 u = *(const us4*)&K[gi];
                us4 w = *(const us4*)&V[gi];
                ks[kk][d4 + 0] = bf2f(u.x); ks[kk][d4 + 1] = bf2f(u.y);
                ks[kk][d4 + 2] = bf2f(u.z); ks[kk][d4 + 3] = bf2f(u.w);
                vs[kk][d4 + 0] = bf2f(w.x); vs[kk][d4 + 1] = bf2f(w.y);
                vs[kk][d4 + 2] = bf2f(w.z); vs[kk][d4 + 3] = bf2f(w.w);
            } else {
                ks[kk][d4 + 0] = 0.f; ks[kk][d4 + 1] = 0.f;
                ks[kk][d4 + 2] = 0.f; ks[kk][d4 + 3] = 0.f;
                vs[kk][d4 + 0] = 0.f; vs[kk][d4 + 1] = 0.f;
                vs[kk][d4 + 2] = 0.f; vs[kk][d4 + 3] = 0.f;
            }
        }
        __syncthreads();

        float s[8];
        #pragma unroll
        for (int j = 0; j < 8; ++j) s[j] = 0.f;
        #pragma unroll
        for (int d2 = 0; d2 < 16; ++d2) {
            float2 kv = *(const float2*)&ks[lane][d2 * 2];
            #pragma unroll
            for (int j = 0; j < 8; ++j) {
                float2 qv = *(const float2*)&qs[wq + j][d2 * 2];
                s[j] += qv.x * kv.x + qv.y * kv.y;
            }
        }
        if (kt * 64 + lane >= BQ) {
            #pragma unroll
            for (int j = 0; j < 8; ++j) s[j] = -1e30f;
        }

        float f[8];
        #pragma unroll
        for (int j = 0; j < 8; ++j) {
            float tm = s[j];
            #pragma unroll
            for (int off = 32; off; off >>= 1) tm = fmaxf(tm, __shfl_xor(tm, off));
            float mn = fmaxf(mrow[j], tm);
            float p = __expf(s[j] - mn);
            f[j] = __expf(mrow[j] - mn);
            mrow[j] = mn;
            float psum = p;
            #pragma unroll
            for (int off = 32; off; off >>= 1) psum += __shfl_xor(psum, off);
            lrow[j] = lrow[j] * f[j] + psum;
            ps[wq + j][lane] = p;
        }
        __syncthreads();

        #pragma unroll
        for (int i = 0; i < 4; ++i) oacc[i] *= f[hi * 4 + i];
        for (int k = 0; k < 64; ++k) {
            float vv = vs[k][dd];
            #pragma unroll
            for (int i = 0; i < 4; ++i)
                oacc[i] += ps[wq + hi * 4 + i][k] * vv;
        }
        __syncthreads();
    }

    #pragma unroll
    for (int i = 0; i < 4; ++i) {
        int qi = wq + hi * 4 + i;
        if (qi < nq) {
            float v = oacc[i] / lrow[hi * 4 + i];
            O[((size_t)(b * BQ + q0 + qi)) * DIM + h * HD + dd] = f2bf(v);
        }
    }
}

// ---------------- LayerNorm: t = X + Y ----------------
__global__ __launch_bounds__(256)
void ln_add(const float* __restrict__ X, const float* __restrict__ Y,
            const float* __restrict__ w, const float* __restrict__ b,
            float* __restrict__ outf, ushort_t* __restrict__ outbf, int ldbf)
{
    const int row = blockIdx.x * 4 + (threadIdx.x >> 6);
    const int lane = threadIdx.x & 63;
    float v[4];
    #pragma unroll
    for (int i = 0; i < 4; ++i) {
        int c = lane + 64 * i;
        v[i] = X[(size_t)row * DIM + c] + Y[(size_t)row * DIM + c];
    }
    float s = v[0] + v[1] + v[2] + v[3];
    float s2 = v[0]*v[0] + v[1]*v[1] + v[2]*v[2] + v[3]*v[3];
    #pragma unroll
    for (int off = 32; off; off >>= 1) { s += __shfl_xor(s, off); s2 += __shfl_xor(s2, off); }
    const float mean = s * (1.0f / DIM);
    const float var = s2 * (1.0f / DIM) - mean * mean;
    const float inv = rsqrtf(var + 1e-5f);
    #pragma unroll
    for (int i = 0; i < 4; ++i) {
        int c = lane + 64 * i;
        float r = (v[i] - mean) * inv * w[c] + b[c];
        if (outf)  outf[(size_t)row * DIM + c] = r;
        if (outbf) outbf[(size_t)row * ldbf + c] = f2bf(r);
    }
}

// ---------------- gated LayerNorm (bf16 inputs) ----------------
__global__ __launch_bounds__(256)
void ln_gate(const ushort_t* __restrict__ C2, const ushort_t* __restrict__ G,
             const float* __restrict__ w, const float* __restrict__ b,
             float* __restrict__ outf, ushort_t* __restrict__ outbf)
{
    const int row = blockIdx.x * 4 + (threadIdx.x >> 6);
    const int lane = threadIdx.x & 63;
    float v[4];
    #pragma unroll
    for (int i = 0; i < 4; ++i) {
        int c = lane + 64 * i;
        float h1 = bf2f(C2[(size_t)row * 512 + c]);
        float ca = bf2f(C2[(size_t)row * 512 + 256 + c]);
        float g1 = bf2f(G[(size_t)row * 512 + c]);
        float g2 = bf2f(G[(size_t)row * 512 + 256 + c]);
        v[i] = g1 * h1 + g2 * ca;
    }
    float s = v[0] + v[1] + v[2] + v[3];
    float s2 = v[0]*v[0] + v[1]*v[1] + v[2]*v[2] + v[3]*v[3];
    #pragma unroll
    for (int off = 32; off; off >>= 1) { s += __shfl_xor(s, off); s2 += __shfl_xor(s2, off); }
    const float mean = s * (1.0f / DIM);
    const float var = s2 * (1.0f / DIM) - mean * mean;
    const float inv = rsqrtf(var + 1e-5f);
    #pragma unroll
    for (int i = 0; i < 4; ++i) {
        int c = lane + 64 * i;
        float r = (v[i] - mean) * inv * w[c] + b[c];
        outf[(size_t)row * DIM + c] = r;
        outbf[(size_t)row * DIM + c] = f2bf(r);
    }
}

// ---------------- softmax over 12 points (padded stride 128) ----------------
__global__ __launch_bounds__(256)
void softmax12(float* __restrict__ awp)
{
    const int i = blockIdx.x * 256 + threadIdx.x;   // 0 .. 76799
    const int row = i >> 3, h = i & 7;
    float* p = awp + (size_t)row * 128 + h * 12;
    float mx = -1e30f;
    #pragma unroll
    for (int j = 0; j < 12; ++j) mx = fmaxf(mx, p[j]);
    float s = 0.0f;
    float e[12];
    #pragma unroll
    for (int j = 0; j < 12; ++j) { e[j] = __expf(p[j] - mx); s += e[j]; }
    const float inv = 1.0f / s;
    #pragma unroll
    for (int j = 0; j < 12; ++j) p[j] = e[j] * inv;
}

// ---------------- deformable sampling -> bf16 into C2[:,256:] ----------------
__global__ __launch_bounds__(256)
void sample_kernel(const float* __restrict__ enc, const float* __restrict__ offs,
                   const float* __restrict__ awp, const float* __restrict__ ref,
                   ushort_t* __restrict__ C2out)
{
    const int bq = blockIdx.x;
    const int b = bq / BQ;
    const int t = threadIdx.x;
    const int h = t >> 5, d = t & 31;
    const float* rp = ref + (size_t)bq * 4;
    const float rx = rp[0], ry = rp[1], rw = rp[2], rh = rp[3];
    const float* op = offs + (size_t)bq * 256 + h * 24;
    const float* ap = awp + (size_t)bq * 128 + h * 12;
    float acc = 0.0f;
    int p = 0;
    #pragma unroll
    for (int l = 0; l < 3; ++l) {
        const int Wl = (l == 0) ? 80 : (l == 1 ? 40 : 20);
        const int Hl = Wl;
        const int soff = (l == 0) ? 0 : (l == 1 ? 6400 : 8000);
        const float* base = enc + ((size_t)(b * SENC + soff)) * DIM + h * HD + d;
        #pragma unroll
        for (int pp = 0; pp < 4; ++pp, ++p) {
            const float ox = op[p * 2 + 0], oy = op[p * 2 + 1];
            const float lx = rx + ox * 0.25f * rw * 0.5f;
            const float ly = ry + oy * 0.25f * rh * 0.5f;
            const float gx = lx * (float)Wl - 0.5f;
            const float gy = ly * (float)Hl - 0.5f;
            const float x0f = floorf(gx), y0f = floorf(gy);
            const int x0 = (int)x0f, y0 = (int)y0f;
            const float wx1 = gx - x0f, wy1 = gy - y0f;
            const float wx0 = 1.0f - wx1, wy0 = 1.0f - wy1;
            float sv = 0.0f;
            const bool vx0 = (x0 >= 0) & (x0 < Wl);
            const bool vx1 = (x0 + 1 >= 0) & (x0 + 1 < Wl);
            const bool vy0 = (y0 >= 0) & (y0 < Hl);
            const bool vy1 = (y0 + 1 >= 0) & (y0 + 1 < Hl);
            if (vx0 & vy0) sv = fmaf(wx0 * wy0, base[((size_t)(y0 * Wl + x0)) * DIM], sv);
            if (vx1 & vy0) sv = fmaf(wx1 * wy0, base[((size_t)(y0 * Wl + x0 + 1)) * DIM], sv);
            if (vx0 & vy1) sv = fmaf(wx0 * wy1, base[((size_t)((y0 + 1) * Wl + x0)) * DIM], sv);
            if (vx1 & vy1) sv = fmaf(wx1 * wy1, base[((size_t)((y0 + 1) * Wl + x0 + 1)) * DIM], sv);
            acc = fmaf(ap[p], sv, acc);
        }
    }
    C2out[(size_t)bq * 512 + 256 + h * HD + d] = f2bf(acc);
}

extern "C" void kernel_launch(void* const* d_in, const int* in_sizes, int n_in,
                              void* d_out, int out_size, void* d_ws, size_t ws_size,
                              hipStream_t stream)
{
    (void)in_sizes; (void)n_in; (void)out_size; (void)ws_size;
    const float* hidden   = (const float*)d_in[0];
    const float* pos      = (const float*)d_in[1];
    const float* ref      = (const float*)d_in[2];
    const float* enc      = (const float*)d_in[3];
    const float* q_w      = (const float*)d_in[4];
    const float* q_b      = (const float*)d_in[5];
    const float* k_w      = (const float*)d_in[6];
    const float* k_b      = (const float*)d_in[7];
    const float* v_w      = (const float*)d_in[8];
    const float* v_b      = (const float*)d_in[9];
    const float* o_w      = (const float*)d_in[10];
    const float* o_b      = (const float*)d_in[11];
    const float* sa_ln_w  = (const float*)d_in[12];
    const float* sa_ln_b  = (const float*)d_in[13];
    const float* off_w    = (const float*)d_in[14];
    const float* off_b    = (const float*)d_in[15];
    const float* aw_w     = (const float*)d_in[16];
    const float* aw_b     = (const float*)d_in[17];
    const float* gate_w   = (const float*)d_in[18];
    const float* gate_b   = (const float*)d_in[19];
    const float* gate_ln_w= (const float*)d_in[20];
    const float* gate_ln_b= (const float*)d_in[21];
    const float* fc1_w    = (const float*)d_in[22];
    const float* fc1_b    = (const float*)d_in[23];
    const float* fc2_w    = (const float*)d_in[24];
    const float* fc2_b    = (const float*)d_in[25];
    const float* fin_ln_w = (const float*)d_in[26];
    const float* fin_ln_b = (const float*)d_in[27];
    float* out = (float*)d_out;

    char* wsb = (char*)d_ws;
    const size_t U = 4915200;          // 9600*128*4 bytes
    ushort_t* hqbf  = (ushort_t*)(wsb + 0);      // S0: hq bf16 -> aobf -> h2bf
    ushort_t* aobf  = hqbf;
    ushort_t* h2bf  = hqbf;
    ushort_t* hidbf = (ushort_t*)(wsb + U);      // S1: hidden bf16 -> awp -> (ffn spans S0..S1)
    float*    awp   = (float*)(wsb + U);
    ushort_t* Qbf   = (ushort_t*)(wsb + 2 * U);  // S2
    ushort_t* Kbf   = (ushort_t*)(wsb + 3 * U);  // S3
    ushort_t* Vbf   = (ushort_t*)(wsb + 4 * U);  // S4
    float*    SA    = (float*)(wsb + 2 * U);     // S2-S3: sa out -> offs -> gates -> midbf
    float*    offs  = (float*)(wsb + 2 * U);
    ushort_t* gatesbf = (ushort_t*)(wsb + 2 * U);
    ushort_t* midbf = (ushort_t*)(wsb + 2 * U);  // S2..S5 (4U)
    ushort_t* C2    = (ushort_t*)(wsb + 5 * U);  // S5-S6: [9600][512] bf16
    float*    ffn   = (float*)(wsb + 0);         // S0-S1 (after h2bf/awp dead)
    ushort_t* wt    = (ushort_t*)(wsb + 7 * U);
    ushort_t* qT   = wt;
    ushort_t* kT   = wt + 65536;
    ushort_t* vT   = wt + 131072;
    ushort_t* oT   = wt + 196608;
    ushort_t* offT = wt + 262144;     // 256 x 256
    ushort_t* awT  = wt + 327680;     // 128 x 256
    ushort_t* gT   = wt + 360448;     // 512 x 512
    ushort_t* f1T  = wt + 622592;     // 1024 x 256
    ushort_t* f2T  = wt + 884736;     // 256 x 1024

    const dim3 blk(256);
    const float scal = 0.17677669529663687f;   // 32^-0.5

    // weight transposes (f32 -> bf16, N-padded with zeros)
    wtrans<<<dim3(8, 8),  blk, 0, stream>>>(q_w,   qT,   256, 256, 256);
    wtrans<<<dim3(8, 8),  blk, 0, stream>>>(k_w,   kT,   256, 256, 256);
    wtrans<<<dim3(8, 8),  blk, 0, stream>>>(v_w,   vT,   256, 256, 256);
    wtrans<<<dim3(8, 8),  blk, 0, stream>>>(o_w,   oT,   256, 256, 256);
    wtrans<<<dim3(8, 8),  blk, 0, stream>>>(off_w, offT, 256, 192, 256);
    wtrans<<<dim3(4, 8),  blk, 0, stream>>>(aw_w,  awT,  256,  96, 128);
    wtrans<<<dim3(16,16), blk, 0, stream>>>(gate_w,gT,   512, 512, 512);
    wtrans<<<dim3(32, 8), blk, 0, stream>>>(fc1_w, f1T,  256,1024,1024);
    wtrans<<<dim3(8, 32), blk, 0, stream>>>(fc2_w, f2T, 1024, 256, 256);

    // activations -> bf16
    cvt_add_bf16<<<dim3(2400), blk, 0, stream>>>(hidden, pos, hqbf, 614400);
    cvt_add_bf16<<<dim3(2400), blk, 0, stream>>>(hidden, nullptr, hidbf, 614400);

    // q/k/v projections (bf16 out)
    gemm_mfma<64,128,0,true><<<dim3(2,150), blk, 0, stream>>>(hqbf, 256, qT, 256, q_b, 256, scal, nullptr, Qbf, 256);
    gemm_mfma<64,128,0,true><<<dim3(2,150), blk, 0, stream>>>(hqbf, 256, kT, 256, k_b, 256, 1.0f, nullptr, Kbf, 256);
    gemm_mfma<64,128,0,true><<<dim3(2,150), blk, 0, stream>>>(hidbf,256, vT, 256, v_b, 256, 1.0f, nullptr, Vbf, 256);

    // self-attention -> aobf (S0)
    attn_flash<<<dim3(2560), blk, 0, stream>>>(Qbf, Kbf, Vbf, aobf);

    // o-projection -> SA f32 (S2-S3); LN(SA + hidden) -> C2[:, :256] bf16
    gemm_mfma<64,128,0,false><<<dim3(2,150), blk, 0, stream>>>(aobf, 256, oT, 256, o_b, 256, 1.0f, SA, nullptr, 256);
    ln_add<<<dim3(2400), blk, 0, stream>>>(SA, hidden, sa_ln_w, sa_ln_b, nullptr, C2, 512);

    // offsets (N=192, padded 256) -> offs f32 (S2-S3); aw (N=96, padded 128) -> awp (S1)
    gemm_mfma<64,128,0,false><<<dim3(2,150), blk, 0, stream>>>(C2, 512, offT, 256, off_b, 192, 1.0f, offs, nullptr, 256);
    gemm_mfma<64,128,0,false><<<dim3(1,150), blk, 0, stream>>>(C2, 512, awT,  256, aw_b,  96, 1.0f, awp,  nullptr, 128);
    softmax12<<<dim3(300), blk, 0, stream>>>(awp);

    // deformable sampling -> C2[:, 256:] bf16
    sample_kernel<<<dim3(MROWS), blk, 0, stream>>>(enc, offs, awp, ref, C2);

    // gates (sigmoid, bf16 out) -> S2-S3; gated LN -> H2 f32 (d_out) + h2bf (S0)
    gemm_mfma<128,128,2,true><<<dim3(4,75), blk, 0, stream>>>(C2, 512, gT, 512, gate_b, 512, 1.0f, nullptr, gatesbf, 512);
    ln_gate<<<dim3(2400), blk, 0, stream>>>(C2, gatesbf, gate_ln_w, gate_ln_b, out, h2bf);

    // FFN: fc1 (relu, bf16 out) -> midbf (S2..S5); fc2 -> ffn f32 (S0-S1); LN(ffn + H2) -> out
    gemm_mfma<128,128,1,true><<<dim3(8,75), blk, 0, stream>>>(h2bf, 256, f1T, 256, fc1_b, 1024, 1.0f, nullptr, midbf, 1024);
    gemm_mfma<64,128,0,false><<<dim3(2,150), blk, 0, stream>>>(midbf, 1024, f2T, 1024, fc2_b, 256, 1.0f, ffn, nullptr, 256);
    ln_add<<<dim3(2400), blk, 0, stream>>>(ffn, out, fin_ln_w, fin_ln_b, out, nullptr, 0);
}

// Round 3
// 349.481 us; speedup vs baseline: 3.1650x; 1.2852x over previous
//
#include <hip/hip_runtime.h>
#include <cmath>

#define BQ 300
#define DIM 256
#define NH 8
#define HD 32
#define NB 32
#define MROWS 9600
#define SENC 8400

typedef unsigned short ushort_t;
typedef __attribute__((ext_vector_type(8))) short short8;
typedef __attribute__((ext_vector_type(4))) float f32x4;
typedef __attribute__((ext_vector_type(4))) unsigned short us4;

__device__ __forceinline__ float bf2f(ushort_t u) {
    union { unsigned u32; float f; } x; x.u32 = ((unsigned)u) << 16; return x.f;
}
__device__ __forceinline__ ushort_t f2bf(float f) {
    union { float f; unsigned u; } x; x.f = f;
    unsigned u = x.u;
    u += 0x7fffu + ((u >> 16) & 1u);
    return (ushort_t)(u >> 16);
}

// ---------------- all weight transposes in ONE kernel ----------------
// Each 32x32 tile transposes W[k][n] -> WT[n][k] (bf16, optional scale).
__global__ __launch_bounds__(256)
void wtrans_all(const float* __restrict__ q_w, const float* __restrict__ k_w,
                const float* __restrict__ v_w, const float* __restrict__ o_w,
                const float* __restrict__ off_w, const float* __restrict__ aw_w,
                const float* __restrict__ gate_w, const float* __restrict__ fc1_w,
                const float* __restrict__ fc2_w,
                ushort_t* __restrict__ qkT, ushort_t* __restrict__ vT,
                ushort_t* __restrict__ oT, ushort_t* __restrict__ offawT,
                ushort_t* __restrict__ gT, ushort_t* __restrict__ f1T,
                ushort_t* __restrict__ f2T,
                const float* __restrict__ q_b, float* __restrict__ qsb,
                float scal)
{
    __shared__ float t[32][33];
    const int bid = blockIdx.x;
    const float* src; ushort_t* dst; int K, N, local; float scale = 1.0f;

    if (bid < 64)       { src = q_w;   dst = qkT;             K = 256; N = 256;  local = bid;       scale = scal; }
    else if (bid < 128) { src = k_w;   dst = qkT + 256 * 256; K = 256; N = 256;  local = bid - 64; }
    else if (bid < 192) { src = v_w;   dst = vT;              K = 256; N = 256;  local = bid - 128; }
    else if (bid < 256) { src = o_w;   dst = oT;              K = 256; N = 256;  local = bid - 192; }
    else if (bid < 304) { src = off_w; dst = offawT;          K = 256; N = 192;  local = bid - 256; }
    else if (bid < 328) { src = aw_w;  dst = offawT + 192 * 256; K = 256; N = 96; local = bid - 304; }
    else if (bid < 336) {   // zero-fill offawT rows 288..319
        int l = bid - 328;
        ushort_t* d2 = offawT + 288 * 256 + l * 32;
        for (int e = threadIdx.x; e < 32 * 32; e += 256) { int r = e >> 5, c = e & 31; d2[r * 256 + c] = 0; }
        return;
    }
    else if (bid < 592) { src = gate_w; dst = gT;  K = 512;  N = 512;  local = bid - 336; }
    else if (bid < 848) { src = fc1_w;  dst = f1T; K = 256;  N = 1024; local = bid - 592; }
    else if (bid < 1104){ src = fc2_w;  dst = f2T; K = 1024; N = 256;  local = bid - 848; }
    else {  // scale q bias
        if (threadIdx.x < 256) qsb[threadIdx.x] = q_b[threadIdx.x] * scal;
        return;
    }
    const int tilesx = N >> 5;
    const int n0 = (local % tilesx) * 32, k0 = (local / tilesx) * 32;
    const int tx = threadIdx.x & 31, ty = threadIdx.x >> 5;
    #pragma unroll
    for (int i = 0; i < 4; ++i)
        t[ty + i * 8][tx] = src[(size_t)(k0 + ty + i * 8) * N + n0 + tx];
    __syncthreads();
    #pragma unroll
    for (int i = 0; i < 4; ++i)
        dst[(size_t)(n0 + ty + i * 8) * K + k0 + tx] = f2bf(t[tx][ty + i * 8] * scale);
}

// ---------------- f32 -> bf16: hq = hidden+pos, hid = hidden ----------------
__global__ __launch_bounds__(256)
void cvt2(const float* __restrict__ hidden, const float* __restrict__ pos,
          ushort_t* __restrict__ hq, ushort_t* __restrict__ hid)
{
    int i = blockIdx.x * 256 + threadIdx.x;
    if (i < 614400) {
        float4 a = ((const float4*)hidden)[i];
        float4 b = ((const float4*)pos)[i];
        us4 u;
        u.x = f2bf(a.x + b.x); u.y = f2bf(a.y + b.y);
        u.z = f2bf(a.z + b.z); u.w = f2bf(a.w + b.w);
        *(us4*)&hq[(size_t)i * 4] = u;
    } else {
        i -= 614400;
        float4 a = ((const float4*)hidden)[i];
        us4 u;
        u.x = f2bf(a.x); u.y = f2bf(a.y); u.z = f2bf(a.z); u.w = f2bf(a.w);
        *(us4*)&hid[(size_t)i * 4] = u;
    }
}

// ---------------- MFMA GEMM ----------------
// C = act(A @ B + bias);  A: M x K bf16 (lda);  Bt: Npad x K bf16 (= B^T)
// bias: cols [0,bsplit) -> bias[], [bsplit,N) -> bias2[], >=N -> 0
template<int BM, int BN, int ACT, bool OBF>
__global__ __launch_bounds__(256)
void gemm_mfma(const ushort_t* __restrict__ A, int lda,
               const ushort_t* __restrict__ Bt, int K,
               const float* __restrict__ bias, const float* __restrict__ bias2,
               int bsplit, int N,
               float* __restrict__ Cf, ushort_t* __restrict__ Cb, int ldc)
{
    constexpr int LDT = 40;
    __shared__ ushort_t As[BM * LDT];
    __shared__ ushort_t Bs[BN * LDT];
    const int tid = threadIdx.x;
    const int row0 = blockIdx.y * BM, col0 = blockIdx.x * BN;
    const int lane = tid & 63, wid = tid >> 6;
    const int wm = wid >> 1, wn = wid & 1;
    constexpr int FM = BM / 32, FN = BN / 32;
    const int r16 = lane & 15, kg = lane >> 4;

    f32x4 acc[FM][FN];
    #pragma unroll
    for (int m = 0; m < FM; ++m)
        #pragma unroll
        for (int n = 0; n < FN; ++n) {
            f32x4 z = {0.f, 0.f, 0.f, 0.f};
            acc[m][n] = z;
        }

    for (int k0 = 0; k0 < K; k0 += 32) {
        #pragma unroll
        for (int c = 0; c < BM * 4 / 256; ++c) {
            int idx = tid + c * 256;
            int r = idx >> 2, cc = idx & 3;
            *(short8*)&As[r * LDT + cc * 8] =
                *(const short8*)&A[(size_t)(row0 + r) * lda + k0 + cc * 8];
        }
        #pragma unroll
        for (int c = 0; c < BN * 4 / 256; ++c) {
            int idx = tid + c * 256;
            int r = idx >> 2, cc = idx & 3;
            *(short8*)&Bs[r * LDT + cc * 8] =
                *(const short8*)&Bt[(size_t)(col0 + r) * K + k0 + cc * 8];
        }
        __syncthreads();
        short8 a[FM], b[FN];
        #pragma unroll
        for (int m = 0; m < FM; ++m)
            a[m] = *(const short8*)&As[(wm * (BM / 2) + m * 16 + r16) * LDT + kg * 8];
        #pragma unroll
        for (int n = 0; n < FN; ++n)
            b[n] = *(const short8*)&Bs[(wn * (BN / 2) + n * 16 + r16) * LDT + kg * 8];
        #pragma unroll
        for (int m = 0; m < FM; ++m)
            #pragma unroll
            for (int n = 0; n < FN; ++n)
                acc[m][n] = __builtin_amdgcn_mfma_f32_16x16x32_bf16(a[m], b[n], acc[m][n], 0, 0, 0);
        __syncthreads();
    }

    #pragma unroll
    for (int m = 0; m < FM; ++m) {
        #pragma unroll
        for (int n = 0; n < FN; ++n) {
            int colb = col0 + wn * (BN / 2) + n * 16 + r16;
            float bs;
            if (colb < bsplit) bs = bias[colb];
            else if (colb < N) bs = bias2[colb - bsplit];
            else bs = 0.0f;
            #pragma unroll
            for (int r = 0; r < 4; ++r) {
                int row = row0 + wm * (BM / 2) + m * 16 + kg * 4 + r;
                float v = acc[m][n][r] + bs;
                if (ACT == 1) v = fmaxf(v, 0.0f);
                if (ACT == 2) v = 1.0f / (1.0f + __expf(-v));
                if (OBF) Cb[(size_t)row * ldc + colb] = f2bf(v);
                else     Cf[(size_t)row * ldc + colb] = v;
            }
        }
    }
}

// ---------------- MFMA flash attention ----------------
// grid 2560 = (b,h,qc); 256 thr = 4 waves. QK buffer: [9600][512] (q | k), V: [9600][256]
__global__ __launch_bounds__(256)
void attn_flash(const ushort_t* __restrict__ QK, const ushort_t* __restrict__ V,
                ushort_t* __restrict__ O)
{
    __shared__ ushort_t ks[64 * 40];
    __shared__ ushort_t vt[32 * 72];
    __shared__ float    ss[32 * 68];
    __shared__ ushort_t ps[32 * 72];
    __shared__ float    ml[32], ll[32], fl[32];

    const int orig = blockIdx.x;
    const int wg = (orig & 7) * 320 + (orig >> 3);   // XCD-contiguous
    const int qc = wg % 10, bh = wg / 10;
    const int b = bh >> 3, h = bh & 7;
    const int q0 = qc * 32;
    const int nq = (BQ - q0 < 32) ? (BQ - q0) : 32;

    const int tid = threadIdx.x;
    const int lane = tid & 63, wid = tid >> 6;
    const int r16 = lane & 15, kg = lane >> 4;
    const int wm = wid >> 1, wn = wid & 1;

    if (tid < 32) { ml[tid] = -1e30f; ll[tid] = 0.f; }

    // Q fragments in registers (both row tiles)
    short8 aq[2];
    #pragma unroll
    for (int rt = 0; rt < 2; ++rt) {
        int qr = q0 + rt * 16 + r16;
        if (qr > BQ - 1) qr = BQ - 1;
        aq[rt] = *(const short8*)&QK[((size_t)(b * BQ + qr)) * 512 + h * 32 + kg * 8];
    }
    f32x4 oacc = {0.f, 0.f, 0.f, 0.f};

    for (int kt = 0; kt < 5; ++kt) {
        __syncthreads();
        // stage K [64][40] and V transposed [32][72]
        {
            int kk = tid >> 2, c8 = (tid & 3) * 8;
            int ki = kt * 64 + kk;
            short8 kv = {0, 0, 0, 0, 0, 0, 0, 0};
            short8 vv = {0, 0, 0, 0, 0, 0, 0, 0};
            if (ki < BQ) {
                kv = *(const short8*)&QK[((size_t)(b * BQ + ki)) * 512 + 256 + h * 32 + c8];
                vv = *(const short8*)&V[((size_t)(b * BQ + ki)) * 256 + h * 32 + c8];
            }
            *(short8*)&ks[kk * 40 + c8] = kv;
            #pragma unroll
            for (int j = 0; j < 8; ++j) vt[(c8 + j) * 72 + kk] = (ushort_t)vv[j];
        }
        __syncthreads();
        // S = Q K^T : wave wid owns key tile [wid*16, wid*16+16)
        {
            short8 bk = *(const short8*)&ks[(wid * 16 + r16) * 40 + kg * 8];
            #pragma unroll
            for (int rt = 0; rt < 2; ++rt) {
                f32x4 sacc = {0.f, 0.f, 0.f, 0.f};
                sacc = __builtin_amdgcn_mfma_f32_16x16x32_bf16(aq[rt], bk, sacc, 0, 0, 0);
                #pragma unroll
                for (int r = 0; r < 4; ++r)
                    ss[(rt * 16 + kg * 4 + r) * 68 + wid * 16 + r16] = sacc[r];
            }
        }
        __syncthreads();
        // online softmax: wave handles rows wid*8 .. +7; lane = key
        #pragma unroll
        for (int j = 0; j < 8; ++j) {
            int row = wid * 8 + j;
            float s = ss[row * 68 + lane];
            if (kt * 64 + lane >= BQ) s = -1e30f;
            float tm = s;
            #pragma unroll
            for (int off = 32; off; off >>= 1) tm = fmaxf(tm, __shfl_xor(tm, off));
            float mold = ml[row];
            float mnew = fmaxf(mold, tm);
            float p = __expf(s - mnew);
            float psum = p;
            #pragma unroll
            for (int off = 32; off; off >>= 1) psum += __shfl_xor(psum, off);
            if (lane == 0) {
                float f = __expf(mold - mnew);
                ml[row] = mnew;
                ll[row] = ll[row] * f + psum;
                fl[row] = f;
            }
            ps[row * 72 + lane] = f2bf(p);
        }
        __syncthreads();
        // O += P V : wave tile rows wm*16.., cols (d) wn*16..
        {
            #pragma unroll
            for (int r = 0; r < 4; ++r)
                oacc[r] *= fl[wm * 16 + kg * 4 + r];
            #pragma unroll
            for (int kstep = 0; kstep < 2; ++kstep) {
                short8 pa = *(const short8*)&ps[(wm * 16 + r16) * 72 + kstep * 32 + kg * 8];
                short8 bv = *(const short8*)&vt[(wn * 16 + r16) * 72 + kstep * 32 + kg * 8];
                oacc = __builtin_amdgcn_mfma_f32_16x16x32_bf16(pa, bv, oacc, 0, 0, 0);
            }
        }
    }
    __syncthreads();
    #pragma unroll
    for (int r = 0; r < 4; ++r) {
        int rowl = wm * 16 + kg * 4 + r;
        if (rowl < nq) {
            float v = oacc[r] / ll[rowl];
            O[((size_t)(b * BQ + q0 + rowl)) * 256 + h * 32 + wn * 16 + r16] = f2bf(v);
        }
    }
}

// ---------------- LayerNorm: t = X + Y ----------------
__global__ __launch_bounds__(256)
void ln_add(const float* __restrict__ X, const float* __restrict__ Y,
            const float* __restrict__ w, const float* __restrict__ b,
            float* __restrict__ outf, ushort_t* __restrict__ outbf, int ldbf)
{
    const int row = blockIdx.x * 4 + (threadIdx.x >> 6);
    const int lane = threadIdx.x & 63;
    float v[4];
    #pragma unroll
    for (int i = 0; i < 4; ++i) {
        int c = lane + 64 * i;
        v[i] = X[(size_t)row * DIM + c] + Y[(size_t)row * DIM + c];
    }
    float s = v[0] + v[1] + v[2] + v[3];
    float s2 = v[0]*v[0] + v[1]*v[1] + v[2]*v[2] + v[3]*v[3];
    #pragma unroll
    for (int off = 32; off; off >>= 1) { s += __shfl_xor(s, off); s2 += __shfl_xor(s2, off); }
    const float mean = s * (1.0f / DIM);
    const float var = s2 * (1.0f / DIM) - mean * mean;
    const float inv = rsqrtf(var + 1e-5f);
    #pragma unroll
    for (int i = 0; i < 4; ++i) {
        int c = lane + 64 * i;
        float r = (v[i] - mean) * inv * w[c] + b[c];
        if (outf)  outf[(size_t)row * DIM + c] = r;
        if (outbf) outbf[(size_t)row * ldbf + c] = f2bf(r);
    }
}

// ---------------- gated LayerNorm ----------------
__global__ __launch_bounds__(256)
void ln_gate(const ushort_t* __restrict__ C2, const ushort_t* __restrict__ G,
             const float* __restrict__ w, const float* __restrict__ b,
             float* __restrict__ outf, ushort_t* __restrict__ outbf)
{
    const int row = blockIdx.x * 4 + (threadIdx.x >> 6);
    const int lane = threadIdx.x & 63;
    float v[4];
    #pragma unroll
    for (int i = 0; i < 4; ++i) {
        int c = lane + 64 * i;
        float h1 = bf2f(C2[(size_t)row * 512 + c]);
        float ca = bf2f(C2[(size_t)row * 512 + 256 + c]);
        float g1 = bf2f(G[(size_t)row * 512 + c]);
        float g2 = bf2f(G[(size_t)row * 512 + 256 + c]);
        v[i] = g1 * h1 + g2 * ca;
    }
    float s = v[0] + v[1] + v[2] + v[3];
    float s2 = v[0]*v[0] + v[1]*v[1] + v[2]*v[2] + v[3]*v[3];
    #pragma unroll
    for (int off = 32; off; off >>= 1) { s += __shfl_xor(s, off); s2 += __shfl_xor(s2, off); }
    const float mean = s * (1.0f / DIM);
    const float var = s2 * (1.0f / DIM) - mean * mean;
    const float inv = rsqrtf(var + 1e-5f);
    #pragma unroll
    for (int i = 0; i < 4; ++i) {
        int c = lane + 64 * i;
        float r = (v[i] - mean) * inv * w[c] + b[c];
        outf[(size_t)row * DIM + c] = r;
        outbf[(size_t)row * DIM + c] = f2bf(r);
    }
}

// ---------------- deformable sampling (softmax fused) ----------------
// offaw: [9600][320] f32 — cols 0..191 raw offsets, 192..287 raw aw logits
__global__ __launch_bounds__(256)
void sample_kernel(const float* __restrict__ enc, const float* __restrict__ offaw,
                   const float* __restrict__ ref, ushort_t* __restrict__ C2out)
{
    const int bq = blockIdx.x;
    const int b = bq / BQ;
    const int t = threadIdx.x;
    const int h = t >> 5, d = t & 31;
    const float* rp = ref + (size_t)bq * 4;
    const float rx = rp[0], ry = rp[1], rw = rp[2], rh = rp[3];
    const float* op = offaw + (size_t)bq * 320 + h * 24;
    const float* ap = offaw + (size_t)bq * 320 + 192 + h * 12;

    // per-thread softmax over the 12 attention logits (broadcast reads)
    float wgt[12];
    float mx = -1e30f;
    #pragma unroll
    for (int j = 0; j < 12; ++j) { wgt[j] = ap[j]; mx = fmaxf(mx, wgt[j]); }
    float sum = 0.0f;
    #pragma unroll
    for (int j = 0; j < 12; ++j) { wgt[j] = __expf(wgt[j] - mx); sum += wgt[j]; }
    const float isum = 1.0f / sum;

    float acc = 0.0f;
    int p = 0;
    #pragma unroll
    for (int l = 0; l < 3; ++l) {
        const int Wl = (l == 0) ? 80 : (l == 1 ? 40 : 20);
        const int Hl = Wl;
        const int soff = (l == 0) ? 0 : (l == 1 ? 6400 : 8000);
        const float* base = enc + ((size_t)(b * SENC + soff)) * DIM + h * HD + d;
        #pragma unroll
        for (int pp = 0; pp < 4; ++pp, ++p) {
            const float ox = op[p * 2 + 0], oy = op[p * 2 + 1];
            const float lx = rx + ox * 0.25f * rw * 0.5f;
            const float ly = ry + oy * 0.25f * rh * 0.5f;
            const float gx = lx * (float)Wl - 0.5f;
            const float gy = ly * (float)Hl - 0.5f;
            const float x0f = floorf(gx), y0f = floorf(gy);
            const int x0 = (int)x0f, y0 = (int)y0f;
            const float wx1 = gx - x0f, wy1 = gy - y0f;
            const float wx0 = 1.0f - wx1, wy0 = 1.0f - wy1;
            float sv = 0.0f;
            const bool vx0 = (x0 >= 0) & (x0 < Wl);
            const bool vx1 = (x0 + 1 >= 0) & (x0 + 1 < Wl);
            const bool vy0 = (y0 >= 0) & (y0 < Hl);
            const bool vy1 = (y0 + 1 >= 0) & (y0 + 1 < Hl);
            if (vx0 & vy0) sv = fmaf(wx0 * wy0, base[((size_t)(y0 * Wl + x0)) * DIM], sv);
            if (vx1 & vy0) sv = fmaf(wx1 * wy0, base[((size_t)(y0 * Wl + x0 + 1)) * DIM], sv);
            if (vx0 & vy1) sv = fmaf(wx0 * wy1, base[((size_t)((y0 + 1) * Wl + x0)) * DIM], sv);
            if (vx1 & vy1) sv = fmaf(wx1 * wy1, base[((size_t)((y0 + 1) * Wl + x0 + 1)) * DIM], sv);
            acc = fmaf(wgt[p] * isum, sv, acc);
        }
    }
    C2out[(size_t)bq * 512 + 256 + h * HD + d] = f2bf(acc);
}

extern "C" void kernel_launch(void* const* d_in, const int* in_sizes, int n_in,
                              void* d_out, int out_size, void* d_ws, size_t ws_size,
                              hipStream_t stream)
{
    (void)in_sizes; (void)n_in; (void)out_size; (void)ws_size;
    const float* hidden   = (const float*)d_in[0];
    const float* pos      = (const float*)d_in[1];
    const float* ref      = (const float*)d_in[2];
    const float* enc      = (const float*)d_in[3];
    const float* q_w      = (const float*)d_in[4];
    const float* q_b      = (const float*)d_in[5];
    const float* k_w      = (const float*)d_in[6];
    const float* k_b      = (const float*)d_in[7];
    const float* v_w      = (const float*)d_in[8];
    const float* v_b      = (const float*)d_in[9];
    const float* o_w      = (const float*)d_in[10];
    const float* o_b      = (const float*)d_in[11];
    const float* sa_ln_w  = (const float*)d_in[12];
    const float* sa_ln_b  = (const float*)d_in[13];
    const float* off_w    = (const float*)d_in[14];
    const float* off_b    = (const float*)d_in[15];
    const float* aw_w     = (const float*)d_in[16];
    const float* aw_b     = (const float*)d_in[17];
    const float* gate_w   = (const float*)d_in[18];
    const float* gate_b   = (const float*)d_in[19];
    const float* gate_ln_w= (const float*)d_in[20];
    const float* gate_ln_b= (const float*)d_in[21];
    const float* fc1_w    = (const float*)d_in[22];
    const float* fc1_b    = (const float*)d_in[23];
    const float* fc2_w    = (const float*)d_in[24];
    const float* fc2_b    = (const float*)d_in[25];
    const float* fin_ln_w = (const float*)d_in[26];
    const float* fin_ln_b = (const float*)d_in[27];
    float* out = (float*)d_out;

    char* wsb = (char*)d_ws;
    ushort_t* hqbf   = (ushort_t*)(wsb + 0);          // [9600][256] bf16
    ushort_t* hidbf  = (ushort_t*)(wsb + 4915200);    // [9600][256] bf16
    ushort_t* QKbuf  = (ushort_t*)(wsb + 9830400);    // [9600][512] bf16
    ushort_t* Vbf    = (ushort_t*)(wsb + 19660800);   // [9600][256] bf16
    ushort_t* aobf   = (ushort_t*)(wsb + 24576000);   // [9600][256] bf16
    float*    SA     = (float*)(wsb + 0);             // [9600][256] f32 (reuse hq/hid)
    ushort_t* C2     = (ushort_t*)(wsb + 9830400);    // [9600][512] bf16 (reuse QK)
    float*    offaw  = (float*)(wsb + 19660800);      // [9600][320] f32 (reuse V/ao)
    ushort_t* gatesbf= (ushort_t*)(wsb + 0);          // [9600][512] bf16 (reuse SA)
    ushort_t* midbf  = (ushort_t*)(wsb + 19660800);   // [9600][1024] bf16 (reuse offaw)
    float*    ffn    = (float*)(wsb + 0);             // [9600][256] f32 (reuse gates)
    ushort_t* h2bf   = (ushort_t*)(wsb + 39321600);   // [9600][256] bf16
    ushort_t* qkT    = (ushort_t*)(wsb + 44236800);   // 512x256
    ushort_t* vT     = (ushort_t*)(wsb + 44498944);   // 256x256
    ushort_t* oT     = (ushort_t*)(wsb + 44630016);   // 256x256
    ushort_t* offawT = (ushort_t*)(wsb + 44761088);   // 320x256
    ushort_t* gT     = (ushort_t*)(wsb + 44924928);   // 512x512
    ushort_t* f1T    = (ushort_t*)(wsb + 45449216);   // 1024x256
    ushort_t* f2T    = (ushort_t*)(wsb + 45973504);   // 256x1024
    float*    qsb    = (float*)(wsb + 46497792);      // 256 f32

    const dim3 blk(256);
    const float scal = 0.17677669529663687f;  // 32^-0.5

    wtrans_all<<<dim3(1105), blk, 0, stream>>>(q_w, k_w, v_w, o_w, off_w, aw_w,
                                               gate_w, fc1_w, fc2_w,
                                               qkT, vT, oT, offawT, gT, f1T, f2T,
                                               q_b, qsb, scal);
    cvt2<<<dim3(4800), blk, 0, stream>>>(hidden, pos, hqbf, hidbf);

    // q|k (N=512) and v projections
    gemm_mfma<128,128,0,true><<<dim3(4,75), blk, 0, stream>>>(hqbf, 256, qkT, 256, qsb, k_b, 256, 512, nullptr, QKbuf, 512);
    gemm_mfma<128,128,0,true><<<dim3(2,75), blk, 0, stream>>>(hidbf, 256, vT, 256, v_b, nullptr, 256, 256, nullptr, Vbf, 256);

    // self-attention
    attn_flash<<<dim3(2560), blk, 0, stream>>>(QKbuf, Vbf, aobf);

    // o-projection -> SA f32; LN(SA + hidden) -> C2[:, :256]
    gemm_mfma<128,128,0,false><<<dim3(2,75), blk, 0, stream>>>(aobf, 256, oT, 256, o_b, nullptr, 256, 256, SA, nullptr, 256);
    ln_add<<<dim3(2400), blk, 0, stream>>>(SA, hidden, sa_ln_w, sa_ln_b, nullptr, C2, 512);

    // offsets|aw combined (N=288, pad 320)
    gemm_mfma<128,64,0,false><<<dim3(5,75), blk, 0, stream>>>(C2, 512, offawT, 256, off_b, aw_b, 192, 288, offaw, nullptr, 320);

    // deformable sampling (softmax fused) -> C2[:, 256:]
    sample_kernel<<<dim3(MROWS), blk, 0, stream>>>(enc, offaw, ref, C2);

    // gates (sigmoid) ; gated LN -> out (H2) + h2bf
    gemm_mfma<128,128,2,true><<<dim3(4,75), blk, 0, stream>>>(C2, 512, gT, 512, gate_b, nullptr, 512, 512, nullptr, gatesbf, 512);
    ln_gate<<<dim3(2400), blk, 0, stream>>>(C2, gatesbf, gate_ln_w, gate_ln_b, out, h2bf);

    // FFN
    gemm_mfma<128,128,1,true><<<dim3(8,75), blk, 0, stream>>>(h2bf, 256, f1T, 256, fc1_b, nullptr, 1024, 1024, nullptr, midbf, 1024);
    gemm_mfma<128,128,0,false><<<dim3(2,75), blk, 0, stream>>>(midbf, 1024, f2T, 1024, fc2_b, nullptr, 256, 256, ffn, nullptr, 256);
    ln_add<<<dim3(2400), blk, 0, stream>>>(ffn, out, fin_ln_w, fin_ln_b, out, nullptr, 0);
}

// Round 4
// 269.103 us; speedup vs baseline: 4.1103x; 1.2987x over previous
//
#include <hip/hip_runtime.h>
#include <cmath>

#define BQ 300
#define DIM 256
#define NH 8
#define HD 32
#define NB 32
#define MROWS 9600
#define SENC 8400

typedef unsigned short ushort_t;
typedef __attribute__((ext_vector_type(8))) short short8;
typedef __attribute__((ext_vector_type(4))) float f32x4;
typedef __attribute__((ext_vector_type(4))) unsigned short us4;

__device__ __forceinline__ float bf2f(ushort_t u) {
    union { unsigned u32; float f; } x; x.u32 = ((unsigned)u) << 16; return x.f;
}
__device__ __forceinline__ ushort_t f2bf(float f) {
    union { float f; unsigned u; } x; x.f = f;
    unsigned u = x.u;
    u += 0x7fffu + ((u >> 16) & 1u);
    return (ushort_t)(u >> 16);
}

// ---------------- all weight transposes in ONE kernel ----------------
__global__ __launch_bounds__(256)
void wtrans_all(const float* __restrict__ q_w, const float* __restrict__ k_w,
                const float* __restrict__ v_w, const float* __restrict__ o_w,
                const float* __restrict__ off_w, const float* __restrict__ aw_w,
                const float* __restrict__ gate_w, const float* __restrict__ fc1_w,
                const float* __restrict__ fc2_w,
                ushort_t* __restrict__ qkT, ushort_t* __restrict__ vT,
                ushort_t* __restrict__ oT, ushort_t* __restrict__ offawT,
                ushort_t* __restrict__ gT, ushort_t* __restrict__ f1T,
                ushort_t* __restrict__ f2T,
                const float* __restrict__ q_b, float* __restrict__ qsb,
                float scal)
{
    __shared__ float t[32][33];
    const int bid = blockIdx.x;
    const float* src; ushort_t* dst; int K, N, local; float scale = 1.0f;

    if (bid < 64)       { src = q_w;   dst = qkT;             K = 256; N = 256;  local = bid;       scale = scal; }
    else if (bid < 128) { src = k_w;   dst = qkT + 256 * 256; K = 256; N = 256;  local = bid - 64; }
    else if (bid < 192) { src = v_w;   dst = vT;              K = 256; N = 256;  local = bid - 128; }
    else if (bid < 256) { src = o_w;   dst = oT;              K = 256; N = 256;  local = bid - 192; }
    else if (bid < 304) { src = off_w; dst = offawT;          K = 256; N = 192;  local = bid - 256; }
    else if (bid < 328) { src = aw_w;  dst = offawT + 192 * 256; K = 256; N = 96; local = bid - 304; }
    else if (bid < 336) {   // zero-fill offawT rows 288..319
        int l = bid - 328;
        ushort_t* d2 = offawT + 288 * 256 + l * 32;
        for (int e = threadIdx.x; e < 32 * 32; e += 256) { int r = e >> 5, c = e & 31; d2[r * 256 + c] = 0; }
        return;
    }
    else if (bid < 592) { src = gate_w; dst = gT;  K = 512;  N = 512;  local = bid - 336; }
    else if (bid < 848) { src = fc1_w;  dst = f1T; K = 256;  N = 1024; local = bid - 592; }
    else if (bid < 1104){ src = fc2_w;  dst = f2T; K = 1024; N = 256;  local = bid - 848; }
    else {  // scale q bias
        if (threadIdx.x < 256) qsb[threadIdx.x] = q_b[threadIdx.x] * scal;
        return;
    }
    const int tilesx = N >> 5;
    const int n0 = (local % tilesx) * 32, k0 = (local / tilesx) * 32;
    const int tx = threadIdx.x & 31, ty = threadIdx.x >> 5;
    #pragma unroll
    for (int i = 0; i < 4; ++i)
        t[ty + i * 8][tx] = src[(size_t)(k0 + ty + i * 8) * N + n0 + tx];
    __syncthreads();
    #pragma unroll
    for (int i = 0; i < 4; ++i)
        dst[(size_t)(n0 + ty + i * 8) * K + k0 + tx] = f2bf(t[tx][ty + i * 8] * scale);
}

// ---------------- f32 -> bf16: hq = hidden+pos, hid = hidden ----------------
__global__ __launch_bounds__(256)
void cvt2(const float* __restrict__ hidden, const float* __restrict__ pos,
          ushort_t* __restrict__ hq, ushort_t* __restrict__ hid)
{
    int i = blockIdx.x * 256 + threadIdx.x;
    if (i < 614400) {
        float4 a = ((const float4*)hidden)[i];
        float4 b = ((const float4*)pos)[i];
        us4 u;
        u.x = f2bf(a.x + b.x); u.y = f2bf(a.y + b.y);
        u.z = f2bf(a.z + b.z); u.w = f2bf(a.w + b.w);
        *(us4*)&hq[(size_t)i * 4] = u;
    } else {
        i -= 614400;
        float4 a = ((const float4*)hidden)[i];
        us4 u;
        u.x = f2bf(a.x); u.y = f2bf(a.y); u.z = f2bf(a.z); u.w = f2bf(a.w);
        *(us4*)&hid[(size_t)i * 4] = u;
    }
}

// ---------------- MFMA GEMM ----------------
template<int BM, int BN, int ACT, bool OBF>
__global__ __launch_bounds__(256)
void gemm_mfma(const ushort_t* __restrict__ A, int lda,
               const ushort_t* __restrict__ Bt, int K,
               const float* __restrict__ bias, const float* __restrict__ bias2,
               int bsplit, int N,
               float* __restrict__ Cf, ushort_t* __restrict__ Cb, int ldc)
{
    constexpr int LDT = 40;
    __shared__ ushort_t As[BM * LDT];
    __shared__ ushort_t Bs[BN * LDT];
    const int tid = threadIdx.x;
    const int row0 = blockIdx.y * BM, col0 = blockIdx.x * BN;
    const int lane = tid & 63, wid = tid >> 6;
    const int wm = wid >> 1, wn = wid & 1;
    constexpr int FM = BM / 32, FN = BN / 32;
    const int r16 = lane & 15, kg = lane >> 4;

    f32x4 acc[FM][FN];
    #pragma unroll
    for (int m = 0; m < FM; ++m)
        #pragma unroll
        for (int n = 0; n < FN; ++n) {
            f32x4 z = {0.f, 0.f, 0.f, 0.f};
            acc[m][n] = z;
        }

    for (int k0 = 0; k0 < K; k0 += 32) {
        #pragma unroll
        for (int c = 0; c < BM * 4 / 256; ++c) {
            int idx = tid + c * 256;
            int r = idx >> 2, cc = idx & 3;
            *(short8*)&As[r * LDT + cc * 8] =
                *(const short8*)&A[(size_t)(row0 + r) * lda + k0 + cc * 8];
        }
        #pragma unroll
        for (int c = 0; c < BN * 4 / 256; ++c) {
            int idx = tid + c * 256;
            int r = idx >> 2, cc = idx & 3;
            *(short8*)&Bs[r * LDT + cc * 8] =
                *(const short8*)&Bt[(size_t)(col0 + r) * K + k0 + cc * 8];
        }
        __syncthreads();
        short8 a[FM], b[FN];
        #pragma unroll
        for (int m = 0; m < FM; ++m)
            a[m] = *(const short8*)&As[(wm * (BM / 2) + m * 16 + r16) * LDT + kg * 8];
        #pragma unroll
        for (int n = 0; n < FN; ++n)
            b[n] = *(const short8*)&Bs[(wn * (BN / 2) + n * 16 + r16) * LDT + kg * 8];
        #pragma unroll
        for (int m = 0; m < FM; ++m)
            #pragma unroll
            for (int n = 0; n < FN; ++n)
                acc[m][n] = __builtin_amdgcn_mfma_f32_16x16x32_bf16(a[m], b[n], acc[m][n], 0, 0, 0);
        __syncthreads();
    }

    #pragma unroll
    for (int m = 0; m < FM; ++m) {
        #pragma unroll
        for (int n = 0; n < FN; ++n) {
            int colb = col0 + wn * (BN / 2) + n * 16 + r16;
            float bs;
            if (colb < bsplit) bs = bias[colb];
            else if (colb < N) bs = bias2[colb - bsplit];
            else bs = 0.0f;
            #pragma unroll
            for (int r = 0; r < 4; ++r) {
                int row = row0 + wm * (BM / 2) + m * 16 + kg * 4 + r;
                float v = acc[m][n][r] + bs;
                if (ACT == 1) v = fmaxf(v, 0.0f);
                if (ACT == 2) v = 1.0f / (1.0f + __expf(-v));
                if (OBF) Cb[(size_t)row * ldc + colb] = f2bf(v);
                else     Cf[(size_t)row * ldc + colb] = v;
            }
        }
    }
}

// ---------------- MFMA flash attention ----------------
__global__ __launch_bounds__(256)
void attn_flash(const ushort_t* __restrict__ QK, const ushort_t* __restrict__ V,
                ushort_t* __restrict__ O)
{
    __shared__ ushort_t ks[64 * 40];
    __shared__ ushort_t vt[32 * 72];
    __shared__ float    ss[32 * 68];
    __shared__ ushort_t ps[32 * 72];
    __shared__ float    ml[32], ll[32], fl[32];

    const int orig = blockIdx.x;
    const int wg = (orig & 7) * 320 + (orig >> 3);   // XCD-contiguous
    const int qc = wg % 10, bh = wg / 10;
    const int b = bh >> 3, h = bh & 7;
    const int q0 = qc * 32;
    const int nq = (BQ - q0 < 32) ? (BQ - q0) : 32;

    const int tid = threadIdx.x;
    const int lane = tid & 63, wid = tid >> 6;
    const int r16 = lane & 15, kg = lane >> 4;
    const int wm = wid >> 1, wn = wid & 1;

    if (tid < 32) { ml[tid] = -1e30f; ll[tid] = 0.f; }

    short8 aq[2];
    #pragma unroll
    for (int rt = 0; rt < 2; ++rt) {
        int qr = q0 + rt * 16 + r16;
        if (qr > BQ - 1) qr = BQ - 1;
        aq[rt] = *(const short8*)&QK[((size_t)(b * BQ + qr)) * 512 + h * 32 + kg * 8];
    }
    f32x4 oacc = {0.f, 0.f, 0.f, 0.f};

    for (int kt = 0; kt < 5; ++kt) {
        __syncthreads();
        {
            int kk = tid >> 2, c8 = (tid & 3) * 8;
            int ki = kt * 64 + kk;
            short8 kv = {0, 0, 0, 0, 0, 0, 0, 0};
            short8 vv = {0, 0, 0, 0, 0, 0, 0, 0};
            if (ki < BQ) {
                kv = *(const short8*)&QK[((size_t)(b * BQ + ki)) * 512 + 256 + h * 32 + c8];
                vv = *(const short8*)&V[((size_t)(b * BQ + ki)) * 256 + h * 32 + c8];
            }
            *(short8*)&ks[kk * 40 + c8] = kv;
            #pragma unroll
            for (int j = 0; j < 8; ++j) vt[(c8 + j) * 72 + kk] = (ushort_t)vv[j];
        }
        __syncthreads();
        {
            short8 bk = *(const short8*)&ks[(wid * 16 + r16) * 40 + kg * 8];
            #pragma unroll
            for (int rt = 0; rt < 2; ++rt) {
                f32x4 sacc = {0.f, 0.f, 0.f, 0.f};
                sacc = __builtin_amdgcn_mfma_f32_16x16x32_bf16(aq[rt], bk, sacc, 0, 0, 0);
                #pragma unroll
                for (int r = 0; r < 4; ++r)
                    ss[(rt * 16 + kg * 4 + r) * 68 + wid * 16 + r16] = sacc[r];
            }
        }
        __syncthreads();
        #pragma unroll
        for (int j = 0; j < 8; ++j) {
            int row = wid * 8 + j;
            float s = ss[row * 68 + lane];
            if (kt * 64 + lane >= BQ) s = -1e30f;
            float tm = s;
            #pragma unroll
            for (int off = 32; off; off >>= 1) tm = fmaxf(tm, __shfl_xor(tm, off));
            float mold = ml[row];
            float mnew = fmaxf(mold, tm);
            float p = __expf(s - mnew);
            float psum = p;
            #pragma unroll
            for (int off = 32; off; off >>= 1) psum += __shfl_xor(psum, off);
            if (lane == 0) {
                float f = __expf(mold - mnew);
                ml[row] = mnew;
                ll[row] = ll[row] * f + psum;
                fl[row] = f;
            }
            ps[row * 72 + lane] = f2bf(p);
        }
        __syncthreads();
        {
            #pragma unroll
            for (int r = 0; r < 4; ++r)
                oacc[r] *= fl[wm * 16 + kg * 4 + r];
            #pragma unroll
            for (int kstep = 0; kstep < 2; ++kstep) {
                short8 pa = *(const short8*)&ps[(wm * 16 + r16) * 72 + kstep * 32 + kg * 8];
                short8 bv = *(const short8*)&vt[(wn * 16 + r16) * 72 + kstep * 32 + kg * 8];
                oacc = __builtin_amdgcn_mfma_f32_16x16x32_bf16(pa, bv, oacc, 0, 0, 0);
            }
        }
    }
    __syncthreads();
    #pragma unroll
    for (int r = 0; r < 4; ++r) {
        int rowl = wm * 16 + kg * 4 + r;
        if (rowl < nq) {
            float v = oacc[r] / ll[rowl];
            O[((size_t)(b * BQ + q0 + rowl)) * 256 + h * 32 + wn * 16 + r16] = f2bf(v);
        }
    }
}

// ---------------- LayerNorm: t = X + Y ----------------
__global__ __launch_bounds__(256)
void ln_add(const float* __restrict__ X, const float* __restrict__ Y,
            const float* __restrict__ w, const float* __restrict__ b,
            float* __restrict__ outf, ushort_t* __restrict__ outbf, int ldbf)
{
    const int row = blockIdx.x * 4 + (threadIdx.x >> 6);
    const int lane = threadIdx.x & 63;
    float v[4];
    #pragma unroll
    for (int i = 0; i < 4; ++i) {
        int c = lane + 64 * i;
        v[i] = X[(size_t)row * DIM + c] + Y[(size_t)row * DIM + c];
    }
    float s = v[0] + v[1] + v[2] + v[3];
    float s2 = v[0]*v[0] + v[1]*v[1] + v[2]*v[2] + v[3]*v[3];
    #pragma unroll
    for (int off = 32; off; off >>= 1) { s += __shfl_xor(s, off); s2 += __shfl_xor(s2, off); }
    const float mean = s * (1.0f / DIM);
    const float var = s2 * (1.0f / DIM) - mean * mean;
    const float inv = rsqrtf(var + 1e-5f);
    #pragma unroll
    for (int i = 0; i < 4; ++i) {
        int c = lane + 64 * i;
        float r = (v[i] - mean) * inv * w[c] + b[c];
        if (outf)  outf[(size_t)row * DIM + c] = r;
        if (outbf) outbf[(size_t)row * ldbf + c] = f2bf(r);
    }
}

// ---------------- gated LayerNorm ----------------
__global__ __launch_bounds__(256)
void ln_gate(const ushort_t* __restrict__ C2, const ushort_t* __restrict__ G,
             const float* __restrict__ w, const float* __restrict__ b,
             float* __restrict__ outf, ushort_t* __restrict__ outbf)
{
    const int row = blockIdx.x * 4 + (threadIdx.x >> 6);
    const int lane = threadIdx.x & 63;
    float v[4];
    #pragma unroll
    for (int i = 0; i < 4; ++i) {
        int c = lane + 64 * i;
        float h1 = bf2f(C2[(size_t)row * 512 + c]);
        float ca = bf2f(C2[(size_t)row * 512 + 256 + c]);
        float g1 = bf2f(G[(size_t)row * 512 + c]);
        float g2 = bf2f(G[(size_t)row * 512 + 256 + c]);
        v[i] = g1 * h1 + g2 * ca;
    }
    float s = v[0] + v[1] + v[2] + v[3];
    float s2 = v[0]*v[0] + v[1]*v[1] + v[2]*v[2] + v[3]*v[3];
    #pragma unroll
    for (int off = 32; off; off >>= 1) { s += __shfl_xor(s, off); s2 += __shfl_xor(s2, off); }
    const float mean = s * (1.0f / DIM);
    const float var = s2 * (1.0f / DIM) - mean * mean;
    const float inv = rsqrtf(var + 1e-5f);
    #pragma unroll
    for (int i = 0; i < 4; ++i) {
        int c = lane + 64 * i;
        float r = (v[i] - mean) * inv * w[c] + b[c];
        outf[(size_t)row * DIM + c] = r;
        outbf[(size_t)row * DIM + c] = f2bf(r);
    }
}

// ---------------- deformable sampling (float4 gathers, 4 queries/block) ----------------
// offaw: [9600][320] f32 — cols 0..191 raw offsets, 192..287 raw aw logits
// thread = (qq, h, d4): 4 queries x 8 heads x 8 channel-quads
__global__ __launch_bounds__(256)
void sample_kernel(const float* __restrict__ enc, const float* __restrict__ offaw,
                   const float* __restrict__ ref, ushort_t* __restrict__ C2out)
{
    __shared__ float sofs[4][320];
    __shared__ float sref[4][4];

    const int orig = blockIdx.x;
    const int blk = (orig & 7) * 300 + (orig >> 3);   // 2400 = 8 * 300, bijective
    const int b = blk / 75;
    const int q0 = (blk % 75) * 4;
    const int tid = threadIdx.x;
    const int qq = tid >> 6;
    const int h = (tid >> 3) & 7;
    const int d4 = tid & 7;
    const int bq = b * BQ + q0 + qq;

    for (int e = tid; e < 4 * 80; e += 256) {
        int row = e >> 6 >= 0 ? e / 80 : 0, c4 = e % 80;
        row = e / 80;
        ((float4*)&sofs[row][0])[c4] =
            ((const float4*)(offaw + (size_t)(b * BQ + q0 + row) * 320))[c4];
    }
    if (tid < 16)
        sref[tid >> 2][tid & 3] = ref[(size_t)(b * BQ + q0 + (tid >> 2)) * 4 + (tid & 3)];
    __syncthreads();

    const float rx = sref[qq][0], ry = sref[qq][1];
    const float rw = sref[qq][2], rh = sref[qq][3];
    const float* op = &sofs[qq][h * 24];
    const float* ap = &sofs[qq][192 + h * 12];

    // softmax over 12 logits (replicated per d4-thread; broadcast LDS reads)
    float wgt[12];
    float mx = -1e30f;
    #pragma unroll
    for (int j = 0; j < 12; ++j) { wgt[j] = ap[j]; mx = fmaxf(mx, wgt[j]); }
    float sum = 0.0f;
    #pragma unroll
    for (int j = 0; j < 12; ++j) { wgt[j] = __expf(wgt[j] - mx); sum += wgt[j]; }
    const float isum = 1.0f / sum;

    f32x4 acc = {0.f, 0.f, 0.f, 0.f};
    int p = 0;
    #pragma unroll
    for (int l = 0; l < 3; ++l) {
        const int Wl = (l == 0) ? 80 : (l == 1 ? 40 : 20);
        const int Hl = Wl;
        const int soff = (l == 0) ? 0 : (l == 1 ? 6400 : 8000);
        const float* base = enc + ((size_t)(b * SENC + soff)) * DIM + h * HD + d4 * 4;
        #pragma unroll
        for (int pp = 0; pp < 4; ++pp, ++p) {
            const float ox = op[p * 2 + 0], oy = op[p * 2 + 1];
            const float lx = rx + ox * 0.25f * rw * 0.5f;
            const float ly = ry + oy * 0.25f * rh * 0.5f;
            const float gx = lx * (float)Wl - 0.5f;
            const float gy = ly * (float)Hl - 0.5f;
            const float x0f = floorf(gx), y0f = floorf(gy);
            const int x0 = (int)x0f, y0 = (int)y0f;
            const float wx1 = gx - x0f, wy1 = gy - y0f;
            const float wx0 = 1.0f - wx1, wy0 = 1.0f - wy1;
            const bool vx0 = (x0 >= 0) & (x0 < Wl);
            const bool vx1 = (x0 + 1 >= 0) & (x0 + 1 < Wl);
            const bool vy0 = (y0 >= 0) & (y0 < Hl);
            const bool vy1 = (y0 + 1 >= 0) & (y0 + 1 < Hl);
            const int xc0 = min(max(x0, 0), Wl - 1);
            const int xc1 = min(max(x0 + 1, 0), Wl - 1);
            const int yc0 = min(max(y0, 0), Hl - 1);
            const int yc1 = min(max(y0 + 1, 0), Hl - 1);
            const float aw2 = wgt[p] * isum;
            const float w00 = wx0 * wy0 * ((vx0 & vy0) ? aw2 : 0.0f);
            const float w10 = wx1 * wy0 * ((vx1 & vy0) ? aw2 : 0.0f);
            const float w01 = wx0 * wy1 * ((vx0 & vy1) ? aw2 : 0.0f);
            const float w11 = wx1 * wy1 * ((vx1 & vy1) ? aw2 : 0.0f);
            f32x4 c00 = *(const f32x4*)&base[((size_t)(yc0 * Wl + xc0)) * DIM];
            f32x4 c10 = *(const f32x4*)&base[((size_t)(yc0 * Wl + xc1)) * DIM];
            f32x4 c01 = *(const f32x4*)&base[((size_t)(yc1 * Wl + xc0)) * DIM];
            f32x4 c11 = *(const f32x4*)&base[((size_t)(yc1 * Wl + xc1)) * DIM];
            #pragma unroll
            for (int r = 0; r < 4; ++r)
                acc[r] += w00 * c00[r] + w10 * c10[r] + w01 * c01[r] + w11 * c11[r];
        }
    }
    us4 u;
    u.x = f2bf(acc[0]); u.y = f2bf(acc[1]); u.z = f2bf(acc[2]); u.w = f2bf(acc[3]);
    *(us4*)&C2out[(size_t)bq * 512 + 256 + h * HD + d4 * 4] = u;
}

extern "C" void kernel_launch(void* const* d_in, const int* in_sizes, int n_in,
                              void* d_out, int out_size, void* d_ws, size_t ws_size,
                              hipStream_t stream)
{
    (void)in_sizes; (void)n_in; (void)out_size; (void)ws_size;
    const float* hidden   = (const float*)d_in[0];
    const float* pos      = (const float*)d_in[1];
    const float* ref      = (const float*)d_in[2];
    const float* enc      = (const float*)d_in[3];
    const float* q_w      = (const float*)d_in[4];
    const float* q_b      = (const float*)d_in[5];
    const float* k_w      = (const float*)d_in[6];
    const float* k_b      = (const float*)d_in[7];
    const float* v_w      = (const float*)d_in[8];
    const float* v_b      = (const float*)d_in[9];
    const float* o_w      = (const float*)d_in[10];
    const float* o_b      = (const float*)d_in[11];
    const float* sa_ln_w  = (const float*)d_in[12];
    const float* sa_ln_b  = (const float*)d_in[13];
    const float* off_w    = (const float*)d_in[14];
    const float* off_b    = (const float*)d_in[15];
    const float* aw_w     = (const float*)d_in[16];
    const float* aw_b     = (const float*)d_in[17];
    const float* gate_w   = (const float*)d_in[18];
    const float* gate_b   = (const float*)d_in[19];
    const float* gate_ln_w= (const float*)d_in[20];
    const float* gate_ln_b= (const float*)d_in[21];
    const float* fc1_w    = (const float*)d_in[22];
    const float* fc1_b    = (const float*)d_in[23];
    const float* fc2_w    = (const float*)d_in[24];
    const float* fc2_b    = (const float*)d_in[25];
    const float* fin_ln_w = (const float*)d_in[26];
    const float* fin_ln_b = (const float*)d_in[27];
    float* out = (float*)d_out;

    char* wsb = (char*)d_ws;
    ushort_t* hqbf   = (ushort_t*)(wsb + 0);          // [9600][256] bf16
    ushort_t* hidbf  = (ushort_t*)(wsb + 4915200);    // [9600][256] bf16
    ushort_t* QKbuf  = (ushort_t*)(wsb + 9830400);    // [9600][512] bf16
    ushort_t* Vbf    = (ushort_t*)(wsb + 19660800);   // [9600][256] bf16
    ushort_t* aobf   = (ushort_t*)(wsb + 24576000);   // [9600][256] bf16
    float*    SA     = (float*)(wsb + 0);             // [9600][256] f32 (reuse hq/hid)
    ushort_t* C2     = (ushort_t*)(wsb + 9830400);    // [9600][512] bf16 (reuse QK)
    float*    offaw  = (float*)(wsb + 19660800);      // [9600][320] f32 (reuse V/ao)
    ushort_t* gatesbf= (ushort_t*)(wsb + 0);          // [9600][512] bf16 (reuse SA)
    ushort_t* midbf  = (ushort_t*)(wsb + 19660800);   // [9600][1024] bf16 (reuse offaw)
    float*    ffn    = (float*)(wsb + 0);             // [9600][256] f32 (reuse gates)
    ushort_t* h2bf   = (ushort_t*)(wsb + 39321600);   // [9600][256] bf16
    ushort_t* qkT    = (ushort_t*)(wsb + 44236800);   // 512x256
    ushort_t* vT     = (ushort_t*)(wsb + 44498944);   // 256x256
    ushort_t* oT     = (ushort_t*)(wsb + 44630016);   // 256x256
    ushort_t* offawT = (ushort_t*)(wsb + 44761088);   // 320x256
    ushort_t* gT     = (ushort_t*)(wsb + 44924928);   // 512x512
    ushort_t* f1T    = (ushort_t*)(wsb + 45449216);   // 1024x256
    ushort_t* f2T    = (ushort_t*)(wsb + 45973504);   // 256x1024
    float*    qsb    = (float*)(wsb + 46497792);      // 256 f32

    const dim3 blk(256);
    const float scal = 0.17677669529663687f;  // 32^-0.5

    wtrans_all<<<dim3(1105), blk, 0, stream>>>(q_w, k_w, v_w, o_w, off_w, aw_w,
                                               gate_w, fc1_w, fc2_w,
                                               qkT, vT, oT, offawT, gT, f1T, f2T,
                                               q_b, qsb, scal);
    cvt2<<<dim3(4800), blk, 0, stream>>>(hidden, pos, hqbf, hidbf);

    // q|k (N=512) and v projections
    gemm_mfma<128,128,0,true><<<dim3(4,75), blk, 0, stream>>>(hqbf, 256, qkT, 256, qsb, k_b, 256, 512, nullptr, QKbuf, 512);
    gemm_mfma<128,128,0,true><<<dim3(2,75), blk, 0, stream>>>(hidbf, 256, vT, 256, v_b, nullptr, 256, 256, nullptr, Vbf, 256);

    // self-attention
    attn_flash<<<dim3(2560), blk, 0, stream>>>(QKbuf, Vbf, aobf);

    // o-projection -> SA f32; LN(SA + hidden) -> C2[:, :256]
    gemm_mfma<128,128,0,false><<<dim3(2,75), blk, 0, stream>>>(aobf, 256, oT, 256, o_b, nullptr, 256, 256, SA, nullptr, 256);
    ln_add<<<dim3(2400), blk, 0, stream>>>(SA, hidden, sa_ln_w, sa_ln_b, nullptr, C2, 512);

    // offsets|aw combined (N=288, pad 320)
    gemm_mfma<128,64,0,false><<<dim3(5,75), blk, 0, stream>>>(C2, 512, offawT, 256, off_b, aw_b, 192, 288, offaw, nullptr, 320);

    // deformable sampling (softmax fused) -> C2[:, 256:]
    sample_kernel<<<dim3(2400), blk, 0, stream>>>(enc, offaw, ref, C2);

    // gates (sigmoid) ; gated LN -> out (H2) + h2bf
    gemm_mfma<128,128,2,true><<<dim3(4,75), blk, 0, stream>>>(C2, 512, gT, 512, gate_b, nullptr, 512, 512, nullptr, gatesbf, 512);
    ln_gate<<<dim3(2400), blk, 0, stream>>>(C2, gatesbf, gate_ln_w, gate_ln_b, out, h2bf);

    // FFN
    gemm_mfma<128,128,1,true><<<dim3(8,75), blk, 0, stream>>>(h2bf, 256, f1T, 256, fc1_b, nullptr, 1024, 1024, nullptr, midbf, 1024);
    gemm_mfma<128,128,0,false><<<dim3(2,75), blk, 0, stream>>>(midbf, 1024, f2T, 1024, fc2_b, nullptr, 256, 256, ffn, nullptr, 256);
    ln_add<<<dim3(2400), blk, 0, stream>>>(ffn, out, fin_ln_w, fin_ln_b, out, nullptr, 0);
}